// Round 1
// baseline (705.882 us; speedup 1.0000x reference)
//
#include <hip/hip_runtime.h>

#define B_ 2048
#define T_ 200
#define D_ 64

constexpr int WAVES = 4;            // waves per block
constexpr int RPW = 2;              // batch rows per wave
constexpr int BLK = WAVES * 64;     // 256 threads
constexpr int ROWS_PB = WAVES * RPW;  // 8 rows per block
constexpr int NBLK = B_ / ROWS_PB;    // 256 blocks -> 1 per CU

__device__ __forceinline__ float sigmoidf_(float x) {
  return 1.0f / (1.0f + __expf(-x));
}
__device__ __forceinline__ float tanhf_(float x) {
  x = fminf(fmaxf(x, -15.0f), 15.0f);
  float e = __expf(2.0f * x);
  return (e - 1.0f) / (e + 1.0f);
}

__global__ __launch_bounds__(BLK) void augru_fp32(
    const float* __restrict__ X, const int* __restrict__ SL,
    const float* __restrict__ ATT, const float* __restrict__ Wg,
    const float* __restrict__ bg, const float* __restrict__ Wc,
    const float* __restrict__ bc, float* __restrict__ OUT) {
  // Weights staged once; reused for all 200 steps.
  __shared__ float sWg[128 * 128];                    // 64 KB, [k][j] row-major
  __shared__ float sWc[128 * 64];                     // 32 KB, [k][d]
  __shared__ __align__(16) float sV[WAVES][RPW][3][64];  // per-wave bcast: x, h, r*h

  const int tid = threadIdx.x;
  for (int i = tid; i < 128 * 128; i += BLK) sWg[i] = Wg[i];
  for (int i = tid; i < 128 * 64; i += BLK) sWc[i] = Wc[i];
  __syncthreads();

  const int wave = tid >> 6;
  const int d = tid & 63;
  const int b0 = blockIdx.x * ROWS_PB + wave * RPW;

  const float bgr = bg[d];
  const float bgu = bg[64 + d];
  const float bcd = bc[d];

  const int L0 = SL[b0];
  const int L1 = SL[b0 + 1];
  const int Lmax = L0 > L1 ? L0 : L1;

  const float* x0 = X + (size_t)b0 * (T_ * D_);
  const float* x1 = x0 + T_ * D_;
  float* o0 = OUT + (size_t)b0 * (T_ * D_);
  float* o1 = o0 + T_ * D_;
  const float* a0 = ATT + (size_t)b0 * T_;
  const float* a1 = a0 + T_;

  float* vx0 = &sV[wave][0][0][0];
  float* vx1 = &sV[wave][1][0][0];
  float* vh0 = &sV[wave][0][1][0];
  float* vh1 = &sV[wave][1][1][0];
  float* vr0 = &sV[wave][0][2][0];
  float* vr1 = &sV[wave][1][2][0];

  float h0 = 0.0f, h1 = 0.0f;
  float xn0 = x0[d];
  float xn1 = x1[d];

  for (int t = 0; t < Lmax; ++t) {
    // Stage current x and h for uniform-address broadcast reads.
    vx0[d] = xn0;
    vx1[d] = xn1;
    vh0[d] = h0;
    vh1[d] = h1;
    asm volatile("s_waitcnt lgkmcnt(0)" ::: "memory");

    // Prefetch next step's x under the matvec compute.
    const int tn = (t + 1 < Lmax) ? t + 1 : t;
    xn0 = x0[tn * D_ + d];
    xn1 = x1[tn * D_ + d];

    float ar0 = bgr, au0 = bgu, ac0 = bcd;
    float ar1 = bgr, au1 = bgu, ac1 = bcd;

    // ---- x contribution: gates (r,u) and candidate ----
#pragma unroll 8
    for (int q = 0; q < 16; ++q) {
      const float4 e0 = *(const float4*)(vx0 + 4 * q);
      const float4 e1 = *(const float4*)(vx1 + 4 * q);
      const float f0[4] = {e0.x, e0.y, e0.z, e0.w};
      const float f1[4] = {e1.x, e1.y, e1.z, e1.w};
#pragma unroll
      for (int i = 0; i < 4; ++i) {
        const int k = 4 * q + i;
        const float wr = sWg[k * 128 + d];
        const float wu = sWg[k * 128 + 64 + d];
        const float wc = sWc[k * 64 + d];
        ar0 = fmaf(f0[i], wr, ar0);
        au0 = fmaf(f0[i], wu, au0);
        ac0 = fmaf(f0[i], wc, ac0);
        ar1 = fmaf(f1[i], wr, ar1);
        au1 = fmaf(f1[i], wu, au1);
        ac1 = fmaf(f1[i], wc, ac1);
      }
    }

    // ---- h contribution: gates (r,u) ----
#pragma unroll 8
    for (int q = 0; q < 16; ++q) {
      const float4 e0 = *(const float4*)(vh0 + 4 * q);
      const float4 e1 = *(const float4*)(vh1 + 4 * q);
      const float f0[4] = {e0.x, e0.y, e0.z, e0.w};
      const float f1[4] = {e1.x, e1.y, e1.z, e1.w};
#pragma unroll
      for (int i = 0; i < 4; ++i) {
        const int k = 64 + 4 * q + i;
        const float wr = sWg[k * 128 + d];
        const float wu = sWg[k * 128 + 64 + d];
        ar0 = fmaf(f0[i], wr, ar0);
        au0 = fmaf(f0[i], wu, au0);
        ar1 = fmaf(f1[i], wr, ar1);
        au1 = fmaf(f1[i], wu, au1);
      }
    }

    const float r0 = sigmoidf_(ar0);
    const float r1 = sigmoidf_(ar1);
    const float u0 = sigmoidf_(au0);
    const float u1 = sigmoidf_(au1);

    vr0[d] = r0 * h0;
    vr1[d] = r1 * h1;
    asm volatile("s_waitcnt lgkmcnt(0)" ::: "memory");

    // ---- (r*h) contribution: candidate ----
#pragma unroll 8
    for (int q = 0; q < 16; ++q) {
      const float4 e0 = *(const float4*)(vr0 + 4 * q);
      const float4 e1 = *(const float4*)(vr1 + 4 * q);
      const float f0[4] = {e0.x, e0.y, e0.z, e0.w};
      const float f1[4] = {e1.x, e1.y, e1.z, e1.w};
#pragma unroll
      for (int i = 0; i < 4; ++i) {
        const int k = 64 + 4 * q + i;
        const float wc = sWc[k * 64 + d];
        ac0 = fmaf(f0[i], wc, ac0);
        ac1 = fmaf(f1[i], wc, ac1);
      }
    }

    const float c0 = tanhf_(ac0);
    const float c1 = tanhf_(ac1);

    const float at0 = a0[t];
    const float at1 = a1[t];
    const float ua0 = at0 * u0;
    const float ua1 = at1 * u1;
    const float hn0 = h0 + ua0 * (c0 - h0);  // (1-ua)h + ua*c
    const float hn1 = h1 + ua1 * (c1 - h1);

    const bool ok0 = t < L0;
    const bool ok1 = t < L1;
    h0 = ok0 ? hn0 : h0;
    h1 = ok1 ? hn1 : h1;
    o0[t * D_ + d] = ok0 ? hn0 : 0.0f;
    o1[t * D_ + d] = ok1 ? hn1 : 0.0f;
  }

  // Zero-fill outputs past this wave's longest sequence.
  for (int t = Lmax; t < T_; ++t) {
    o0[t * D_ + d] = 0.0f;
    o1[t * D_ + d] = 0.0f;
  }
}

extern "C" void kernel_launch(void* const* d_in, const int* in_sizes, int n_in,
                              void* d_out, int out_size, void* d_ws, size_t ws_size,
                              hipStream_t stream) {
  (void)in_sizes; (void)n_in; (void)d_ws; (void)ws_size; (void)out_size;
  const float* X  = (const float*)d_in[0];
  const int*   SL = (const int*)d_in[1];
  const float* A  = (const float*)d_in[2];
  const float* Wg = (const float*)d_in[3];
  const float* bg = (const float*)d_in[4];
  const float* Wc = (const float*)d_in[5];
  const float* bc = (const float*)d_in[6];
  float* O = (float*)d_out;

  augru_fp32<<<NBLK, BLK, 0, stream>>>(X, SL, A, Wg, bg, Wc, bc, O);
}

// Round 2
// 235.081 us; speedup vs baseline: 3.0027x; 3.0027x over previous
//
#include <hip/hip_runtime.h>

#define B_ 2048
#define T_ 200
#define D_ 64

constexpr int WAVES = 4;         // waves per block, 1 batch row per wave
constexpr int BLK = WAVES * 64;  // 256 threads
constexpr int NBLK = B_ / WAVES; // 512 blocks -> 2 per CU

typedef _Float16 half_t;
typedef __attribute__((ext_vector_type(2))) _Float16 h2;

#if defined(__has_builtin)
#if __has_builtin(__builtin_amdgcn_fdot2)
#define HAS_FDOT2 1
#endif
#endif

__device__ __forceinline__ float dot2f(h2 a, h2 b, float c) {
#ifdef HAS_FDOT2
  return __builtin_amdgcn_fdot2(a, b, c, false);
#else
  return fmaf((float)a[0], (float)b[0], fmaf((float)a[1], (float)b[1], c));
#endif
}

__device__ __forceinline__ float sigmoidf_(float x) {
  return 1.0f / (1.0f + __expf(-x));
}
__device__ __forceinline__ float tanhf_(float x) {
  x = fminf(fmaxf(x, -15.0f), 15.0f);
  float e = __expf(2.0f * x);
  return (e - 1.0f) / (e + 1.0f);
}

__global__ __launch_bounds__(BLK, 2) void augru_dot2(
    const float* __restrict__ X, const int* __restrict__ SL,
    const float* __restrict__ ATT, const float* __restrict__ Wg,
    const float* __restrict__ bg, const float* __restrict__ Wc,
    const float* __restrict__ bc, float* __restrict__ OUT) {
  // Per-wave broadcast scratch: [x(64) | h(64) | rh(64)] as fp16.
  __shared__ __align__(16) half_t sV[WAVES][192];

  const int tid = threadIdx.x;
  const int wave = tid >> 6;
  const int d = tid & 63;
  const int b = blockIdx.x * WAVES + wave;

  // ---- Weights for output column d, held in VGPRs as fp16 pairs ----
  // wr[k2] = Wg[2k2 : 2k2+2, d]        (reset gate)
  // wu[k2] = Wg[2k2 : 2k2+2, 64+d]     (update gate)
  // wc[k2] = Wc[2k2 : 2k2+2, d]        (candidate)
  h2 wr[64], wu[64], wc[64];
#pragma unroll
  for (int k2 = 0; k2 < 64; ++k2) {
    const float r0 = Wg[(2 * k2) * 128 + d];
    const float r1 = Wg[(2 * k2 + 1) * 128 + d];
    h2 vr_;
    vr_[0] = (half_t)r0;
    vr_[1] = (half_t)r1;
    wr[k2] = vr_;
    const float u0 = Wg[(2 * k2) * 128 + 64 + d];
    const float u1 = Wg[(2 * k2 + 1) * 128 + 64 + d];
    h2 vu_;
    vu_[0] = (half_t)u0;
    vu_[1] = (half_t)u1;
    wu[k2] = vu_;
    const float c0 = Wc[(2 * k2) * 64 + d];
    const float c1 = Wc[(2 * k2 + 1) * 64 + d];
    h2 vc_;
    vc_[0] = (half_t)c0;
    vc_[1] = (half_t)c1;
    wc[k2] = vc_;
  }

  const float bgr = bg[d];
  const float bgu = bg[64 + d];
  const float bcd = bc[d];

  const int L = SL[b];
  const float* __restrict__ xrow = X + (size_t)b * (T_ * D_);
  const float* __restrict__ arow = ATT + (size_t)b * T_;
  float* __restrict__ orow = OUT + (size_t)b * (T_ * D_);

  half_t* __restrict__ vh = &sV[wave][0];
  const uint4* __restrict__ v4p = (const uint4*)vh;  // 24 x 16B: x q0..7, h q8..15, rh q16..23

  float h = 0.0f;
  float xn = xrow[d];    // x_0 prefetched
  float an = arow[0];    // a_0 prefetched

  for (int t = 0; t < L; ++t) {
    const float a_t = an;
    // Stage x_t and h as fp16 for uniform broadcast reads.
    vh[d] = (half_t)xn;
    vh[64 + d] = (half_t)h;
    asm volatile("s_waitcnt lgkmcnt(0)" ::: "memory");

    // Prefetch next step's x and att under the matvec.
    const int tn = (t + 1 < L) ? t + 1 : t;
    const float xnn = xrow[tn * D_ + d];
    const float ann = arow[tn];

    float ar = bgr, au = bgu, ac = bcd;

    // ---- gates over k=0..127 ([x|h]); candidate x-part (k<64) fused in ----
#pragma unroll
    for (int q = 0; q < 16; ++q) {
      const uint4 blk = v4p[q];
      const h2 e0 = __builtin_bit_cast(h2, blk.x);
      const h2 e1 = __builtin_bit_cast(h2, blk.y);
      const h2 e2 = __builtin_bit_cast(h2, blk.z);
      const h2 e3 = __builtin_bit_cast(h2, blk.w);
      ar = dot2f(e0, wr[4 * q + 0], ar);
      ar = dot2f(e1, wr[4 * q + 1], ar);
      ar = dot2f(e2, wr[4 * q + 2], ar);
      ar = dot2f(e3, wr[4 * q + 3], ar);
      au = dot2f(e0, wu[4 * q + 0], au);
      au = dot2f(e1, wu[4 * q + 1], au);
      au = dot2f(e2, wu[4 * q + 2], au);
      au = dot2f(e3, wu[4 * q + 3], au);
      if (q < 8) {
        ac = dot2f(e0, wc[4 * q + 0], ac);
        ac = dot2f(e1, wc[4 * q + 1], ac);
        ac = dot2f(e2, wc[4 * q + 2], ac);
        ac = dot2f(e3, wc[4 * q + 3], ac);
      }
    }

    const float r = sigmoidf_(ar);
    const float u = sigmoidf_(au);

    // Stage r*h for the candidate's second half.
    vh[128 + d] = (half_t)(r * h);
    asm volatile("s_waitcnt lgkmcnt(0)" ::: "memory");

#pragma unroll
    for (int q = 0; q < 8; ++q) {
      const uint4 blk = v4p[16 + q];
      const h2 e0 = __builtin_bit_cast(h2, blk.x);
      const h2 e1 = __builtin_bit_cast(h2, blk.y);
      const h2 e2 = __builtin_bit_cast(h2, blk.z);
      const h2 e3 = __builtin_bit_cast(h2, blk.w);
      ac = dot2f(e0, wc[32 + 4 * q + 0], ac);
      ac = dot2f(e1, wc[32 + 4 * q + 1], ac);
      ac = dot2f(e2, wc[32 + 4 * q + 2], ac);
      ac = dot2f(e3, wc[32 + 4 * q + 3], ac);
    }

    const float c = tanhf_(ac);
    const float ua = a_t * u;
    const float hn = h + ua * (c - h);  // (1-ua)*h + ua*c
    h = hn;
    orow[t * D_ + d] = hn;  // t < L always inside the loop: no masking needed

    xn = xnn;
    an = ann;
  }

  // Zero-fill outputs past this row's sequence length.
  for (int t = L; t < T_; ++t) {
    orow[t * D_ + d] = 0.0f;
  }
}

extern "C" void kernel_launch(void* const* d_in, const int* in_sizes, int n_in,
                              void* d_out, int out_size, void* d_ws, size_t ws_size,
                              hipStream_t stream) {
  (void)in_sizes; (void)n_in; (void)d_ws; (void)ws_size; (void)out_size;
  const float* X  = (const float*)d_in[0];
  const int*   SL = (const int*)d_in[1];
  const float* A  = (const float*)d_in[2];
  const float* Wg = (const float*)d_in[3];
  const float* bg = (const float*)d_in[4];
  const float* Wc = (const float*)d_in[5];
  const float* bc = (const float*)d_in[6];
  float* O = (float*)d_out;

  augru_dot2<<<NBLK, BLK, 0, stream>>>(X, SL, A, Wg, bg, Wc, bc, O);
}